// Round 2
// baseline (1745.379 us; speedup 1.0000x reference)
//
#include <hip/hip_runtime.h>
#include <stdint.h>

#define BETA 0.9f

// ---------------------------------------------------------------------------
// Kernel 1: transpose fw1 (256, 1152) -> fw1T (1152, 256) so the fc1 spike
// row-gather is coalesced (row i = 256 contiguous floats = 1KB).
// ---------------------------------------------------------------------------
__global__ void transpose_fw1(const float* __restrict__ A, float* __restrict__ At) {
    __shared__ float tile[32][33];
    const int i0 = blockIdx.x * 32;   // i dim (1152)
    const int j0 = blockIdx.y * 32;   // j dim (256)
    const int tx = threadIdx.x, ty = threadIdx.y;
    for (int r = ty; r < 32; r += 8)
        tile[r][tx] = A[(j0 + r) * 1152 + i0 + tx];      // coalesced read over i
    __syncthreads();
    for (int r = ty; r < 32; r += 8)
        At[(i0 + r) * 256 + j0 + tx] = tile[tx][r];      // coalesced write over j
}

// ---------------------------------------------------------------------------
// Kernel 2: R18 = layer-pipelined schedule. R16 shape kept (768 thr, 2 elem,
// 2 blocks/CU) but per phase tau the FIVE layers run CONCURRENTLY on
// different timesteps / waves:
//   wave 0 : conv1(tau)      + fc2(tau-4)
//   waves1-2: conv2(tau-1)   + conv3(tau-2)   (each wave: 5 l's c2, 9 l's c3)
//   waves3-5: fc1-partials(tau-3), 2 groups/wave, 8-wide float4 batches
//   section B (post-barrier): fc1-reduce + LIF4 (tl<256)
// 2 barriers per timestep instead of 4; fc1 L2 latency hides under conv2/3.
// rm1/cm2 are x4-buffered (mod-4 by step) so zeroing-for-next never touches
// the buffer conv2/conv3 are reading this phase. s1e/masks/s4 x2 by parity.
// Every per-output FP chain (term set incl. exact-zero padding, order, FMA
// form) is identical to R16 -> absmax 0.0 expected.
// ---------------------------------------------------------------------------
__global__ __launch_bounds__(768)
__attribute__((amdgpu_waves_per_eu(6)))
void snn_main(
    const float* __restrict__ x,      // (1024, 1, 30, 100)
    const float* __restrict__ w1, const float* __restrict__ b1,
    const float* __restrict__ w2, const float* __restrict__ b2,
    const float* __restrict__ w3, const float* __restrict__ b3,
    const float* __restrict__ fw1T,   // (1152, 256) transposed
    const float* __restrict__ fb1,
    const float* __restrict__ fw2, const float* __restrict__ fb2,
    float* __restrict__ out)          // (100, 1024, 10)
{
    const int b    = blockIdx.x;
    const int tid  = threadIdx.x;
    const int e    = (tid >= 384) ? 1 : 0;
    const int tl   = tid - 384 * e;
    const int lane = tl & 63;
    const int ew   = tl >> 6;               // wave-in-element 0..5

    __shared__ float w2L[16 * 5 * 32];      // 10 KB (shared by both elements)
    __shared__ float w3L[32 * 3 * 64];      // 24 KB
    __shared__ float s1e[2][2][384];        // [e][t&1][c1*24+l]  6 KB
    __shared__ float pacc[2][6][256];       // fc1 partials       12 KB
    __shared__ float s4v[2][2][256];        // [e][t&1][j]        4 KB
    __shared__ unsigned long long masks[2][2][18];  // [e][t&1][l] s3 spikes
    __shared__ unsigned int rm1[2][4][16];  // [e][t&3][c1] s1 row masks
    __shared__ unsigned int cm2[2][4][20];  // [e][t&3][l]  s2 channel masks

    // ---- stage weights into LDS (shared by both elements) ----
    for (int i = tid; i < 16 * 5 * 32; i += 768) {
        const int cc = i & 31, r = i >> 5;          // r = ci*5+k
        w2L[i] = w2[cc * 80 + r];
    }
    for (int i = tid; i < 32 * 3 * 64; i += 768) {
        const int cc = i & 63, r = i >> 6;          // r = ci*3+k
        w3L[i] = w3[cc * 96 + r];
    }
    if (tl < 16) {
        rm1[e][0][tl] = 0u; rm1[e][1][tl] = 0u;
        rm1[e][2][tl] = 0u; rm1[e][3][tl] = 0u;
    }
    if (tl < 20) {
        cm2[e][0][tl] = 0u; cm2[e][1][tl] = 0u;
        cm2[e][2][tl] = 0u; cm2[e][3][tl] = 0u;
    }

    // ---- static per-thread roles ----
    // wave 0: conv1 (4 l-chunks of 6) + fc2
    const int c1 = lane & 15;
    const int l1 = (lane >> 4) * 6;          // {0,6,12,18}
    // waves 1-2: conv2 (5 l's each quarter) + conv3 (9 l's per wave)
    const int c2 = lane & 31;
    const int q2 = (ew == 2) ? (2 + (lane >> 5)) : (lane >> 5);
    const int l0 = q2 * 5;                   // conv2 l-base (5 outputs)
    const unsigned wmask2 = 0x1FFu << l0;    // 9-bit input window
    const int c3 = lane;
    const int l3b = (ew - 1) * 9;            // conv3 l-base (9 outputs)
    // fc2 roles (wave 0)
    const int chf = lane & 15;
    const int jb  = lane >> 4;               // 0..3

    // ---- per-thread register state ----
    const float b1r = (ew == 0) ? b1[c1] : 0.0f;
    float w1r[7];
#pragma unroll
    for (int k = 0; k < 7; ++k) w1r[k] = (ew == 0) ? w1[c1 * 7 + k] : 0.0f;
    const bool cw = (ew == 1 || ew == 2);
    const float b2r = cw ? b2[c2] : 0.0f;
    const float b3r = cw ? b3[c3] : 0.0f;
    const float fb1r = (tl < 256) ? fb1[tl] : 0.0f;

    float m1[6] = {0.f, 0.f, 0.f, 0.f, 0.f, 0.f};
    float m2[5] = {0.f, 0.f, 0.f, 0.f, 0.f};
    float m3[9] = {0.f, 0.f, 0.f, 0.f, 0.f, 0.f, 0.f, 0.f, 0.f};
    float m4 = 0.f;
    float m5[3] = {0.f, 0.f, 0.f};

    const float* xb = x + (2 * b + e) * 3000;
    const int out_b = (2 * b + e) * 10;
    const float4* fw1Tv = reinterpret_cast<const float4*>(fw1T);

    __syncthreads();   // staging -> pipeline

    for (int tau = 0; tau < 104; ++tau) {
        // ================= Section A: all stages in parallel =================
        if (ew == 0) {
            // ---- conv1(t1 = tau): issue x loads first, fc2 fills latency ----
            float xr[12];
            const bool c1v = (tau <= 99);
            if (c1v) {
                if (lane < 16) rm1[e][(tau + 1) & 3][lane] = 0u;  // zero for t+1
#pragma unroll
                for (int r = 0; r < 12; ++r) xr[r] = xb[(l1 + r) * 100 + tau];
            }
            // ---- fc2(t5 = tau-4): 3 passes of 4 outputs, width-16 reduce ----
            if (tau >= 4) {
                const int t5 = tau - 4;
                const float* s4p = &s4v[e][t5 & 1][0];
#pragma unroll
                for (int pi = 0; pi < 3; ++pi) {
                    const int jj = jb + 4 * pi;
                    if (jj < 10) {
                        const float* wrow = fw2 + jj * 256;   // L1-hot
                        float p = 0.f;
#pragma unroll
                        for (int i = 0; i < 16; ++i)
                            p += s4p[i * 16 + chf] * wrow[i * 16 + chf];
                        p += __shfl_xor(p, 8, 16);
                        p += __shfl_xor(p, 4, 16);
                        p += __shfl_xor(p, 2, 16);
                        p += __shfl_xor(p, 1, 16);
                        if (chf == 0) {
                            float h = fb2[jj] + p;
                            float rs = (m5[pi] > 1.0f) ? 1.0f : 0.0f;
                            m5[pi] = BETA * m5[pi] + h - rs;
                            out[t5 * 10240 + out_b + jj] =
                                (m5[pi] > 1.0f) ? 1.0f : 0.0f;
                        }
                    }
                }
            }
            // ---- conv1 compute (6 outputs/thread) ----
            if (c1v) {
#pragma unroll
                for (int j = 0; j < 6; ++j) {
                    float h = b1r;
#pragma unroll
                    for (int k = 0; k < 7; ++k) h += xr[j + k] * w1r[k];
                    float rs = (m1[j] > 1.0f) ? 1.0f : 0.0f;
                    m1[j] = BETA * m1[j] + h - rs;
                    float sa = (m1[j] > 1.0f) ? 1.0f : 0.0f;
                    s1e[e][tau & 1][c1 * 24 + l1 + j] = sa;
                    if (sa != 0.0f)
                        atomicOr(&rm1[e][tau & 3][c1], 1u << (l1 + j));
                }
            }
        } else if (ew <= 2) {
            // ---- conv2(t2 = tau-1): 5 outputs/thread ----
            const int t2 = tau - 1;
            if (t2 >= 0 && t2 <= 99) {
                if (ew == 1 && lane < 20) cm2[e][(t2 + 1) & 3][lane] = 0u;
                const int pb2 = t2 & 3, sp1 = t2 & 1;
                float h[5] = {b2r, b2r, b2r, b2r, b2r};
#pragma unroll
                for (int ci = 0; ci < 16; ++ci) {
                    const unsigned rmv =
                        __builtin_amdgcn_readfirstlane(rm1[e][pb2][ci]);
                    if ((rmv & wmask2) == 0u) continue;  // exact: 0*w skipped
                    float win[9];
#pragma unroll
                    for (int r = 0; r < 9; ++r)
                        win[r] = s1e[e][sp1][ci * 24 + l0 + r];
                    float wk[5];
#pragma unroll
                    for (int k = 0; k < 5; ++k)
                        wk[k] = w2L[(ci * 5 + k) * 32 + c2];
#pragma unroll
                    for (int li = 0; li < 5; ++li)
#pragma unroll
                        for (int k = 0; k < 5; ++k)
                            h[li] += win[li + k] * wk[k];
                }
#pragma unroll
                for (int li = 0; li < 5; ++li) {
                    float rs = (m2[li] > 1.0f) ? 1.0f : 0.0f;
                    m2[li] = BETA * m2[li] + h[li] - rs;
                    if (m2[li] > 1.0f)
                        atomicOr(&cm2[e][pb2][l0 + li], 1u << c2);
                }
            }
            // ---- conv3(t3 = tau-2): 9 outputs/lane-channel ----
            const int t3 = tau - 2;
            if (t3 >= 0 && t3 <= 99) {
                const int pb3 = t3 & 3;
                float h3[9];
#pragma unroll
                for (int li = 0; li < 9; ++li) h3[li] = b3r;
#pragma unroll
                for (int wl = 0; wl < 11; ++wl) {   // window positions
                    unsigned cm =
                        __builtin_amdgcn_readfirstlane(cm2[e][pb3][l3b + wl]);
                    while (cm) {               // scalar mask walk
                        const int ci = (int)__builtin_ctz(cm); cm &= cm - 1;
                        const float* wp = &w3L[ci * 192 + c3];   // + k*64
#pragma unroll
                        for (int k = 0; k < 3; ++k) {
                            const int li = wl - k;               // compile-time
                            if (li >= 0 && li < 9)
                                h3[li] += wp[k * 64];
                        }
                    }
                }
#pragma unroll
                for (int li = 0; li < 9; ++li) {
                    float rs = (m3[li] > 1.0f) ? 1.0f : 0.0f;
                    m3[li] = BETA * m3[li] + h3[li] - rs;
                    float s = (m3[li] > 1.0f) ? 1.0f : 0.0f;
                    unsigned long long mk = __ballot(s != 0.0f);
                    if (lane == 0) masks[e][t3 & 1][l3b + li] = mk;
                }
            }
        } else {
            // ---- fc1 partials (t4 = tau-3): 2 groups/wave, 8-wide float4 ----
            if (tau >= 3 && tau <= 102) {
                const int sp = (tau - 3) & 1;
                const int w = ew - 3;
#pragma unroll
                for (int gi = 0; gi < 2; ++gi) {
                    const int g = w + 3 * gi;
                    float4 acc4; acc4.x = acc4.y = acc4.z = acc4.w = 0.0f;
#pragma unroll 1
                    for (int li3 = 0; li3 < 3; ++li3) {
                        const int l = g + 6 * li3;
                        const unsigned* mp = (const unsigned*)&masks[e][sp][l];
                        const unsigned mlo = __builtin_amdgcn_readfirstlane(mp[0]);
                        const unsigned mhi = __builtin_amdgcn_readfirstlane(mp[1]);
                        unsigned long long mk =
                            ((unsigned long long)mhi << 32) | mlo;
                        while (mk) {   // 8-wide batching (trailing +0 = exact)
                            float4 f0, f1, f2, f3, f4, f5, f6, f7;
                            f0.x=f0.y=f0.z=f0.w=0.f;
                            f1=f0; f2=f0; f3=f0; f4=f0; f5=f0; f6=f0; f7=f0;
                            int c;
                            c = (int)__builtin_ctzll(mk); mk &= mk - 1;
                            f0 = fw1Tv[(c * 18 + l) * 64 + lane];
                            if (mk) { c = (int)__builtin_ctzll(mk); mk &= mk - 1;
                                      f1 = fw1Tv[(c * 18 + l) * 64 + lane]; }
                            if (mk) { c = (int)__builtin_ctzll(mk); mk &= mk - 1;
                                      f2 = fw1Tv[(c * 18 + l) * 64 + lane]; }
                            if (mk) { c = (int)__builtin_ctzll(mk); mk &= mk - 1;
                                      f3 = fw1Tv[(c * 18 + l) * 64 + lane]; }
                            if (mk) { c = (int)__builtin_ctzll(mk); mk &= mk - 1;
                                      f4 = fw1Tv[(c * 18 + l) * 64 + lane]; }
                            if (mk) { c = (int)__builtin_ctzll(mk); mk &= mk - 1;
                                      f5 = fw1Tv[(c * 18 + l) * 64 + lane]; }
                            if (mk) { c = (int)__builtin_ctzll(mk); mk &= mk - 1;
                                      f6 = fw1Tv[(c * 18 + l) * 64 + lane]; }
                            if (mk) { c = (int)__builtin_ctzll(mk); mk &= mk - 1;
                                      f7 = fw1Tv[(c * 18 + l) * 64 + lane]; }
                            acc4.x += f0.x; acc4.y += f0.y; acc4.z += f0.z; acc4.w += f0.w;
                            acc4.x += f1.x; acc4.y += f1.y; acc4.z += f1.z; acc4.w += f1.w;
                            acc4.x += f2.x; acc4.y += f2.y; acc4.z += f2.z; acc4.w += f2.w;
                            acc4.x += f3.x; acc4.y += f3.y; acc4.z += f3.z; acc4.w += f3.w;
                            acc4.x += f4.x; acc4.y += f4.y; acc4.z += f4.z; acc4.w += f4.w;
                            acc4.x += f5.x; acc4.y += f5.y; acc4.z += f5.z; acc4.w += f5.w;
                            acc4.x += f6.x; acc4.y += f6.y; acc4.z += f6.z; acc4.w += f6.w;
                            acc4.x += f7.x; acc4.y += f7.y; acc4.z += f7.z; acc4.w += f7.w;
                        }
                    }
                    ((float4*)&pacc[e][g][0])[lane] = acc4;
                }
            }
        }
        __syncthreads();   // section A -> section B

        // ====== Section B: fc1 reduce + LIF4 (same step t4 = tau-3) ======
        if (tau >= 3 && tau <= 102 && tl < 256) {
            const int t4 = tau - 3;
            float acc = fb1r;
#pragma unroll
            for (int w = 0; w < 6; ++w) acc += pacc[e][w][tl];
            float rs = (m4 > 1.0f) ? 1.0f : 0.0f;
            m4 = BETA * m4 + acc - rs;
            s4v[e][t4 & 1][tl] = (m4 > 1.0f) ? 1.0f : 0.0f;
        }
        __syncthreads();   // phase end
    }
}

extern "C" void kernel_launch(void* const* d_in, const int* in_sizes, int n_in,
                              void* d_out, int out_size, void* d_ws, size_t ws_size,
                              hipStream_t stream) {
    const float* x   = (const float*)d_in[0];
    const float* w1  = (const float*)d_in[1];
    const float* b1  = (const float*)d_in[2];
    const float* w2  = (const float*)d_in[3];
    const float* b2  = (const float*)d_in[4];
    const float* w3  = (const float*)d_in[5];
    const float* b3  = (const float*)d_in[6];
    const float* fw1 = (const float*)d_in[7];
    const float* fb1 = (const float*)d_in[8];
    const float* fw2 = (const float*)d_in[9];
    const float* fb2 = (const float*)d_in[10];
    float* out  = (float*)d_out;
    float* fw1T = (float*)d_ws;   // 1152*256*4 = 1.18 MB

    dim3 tb(32, 8);
    dim3 tg(1152 / 32, 256 / 32);
    transpose_fw1<<<tg, tb, 0, stream>>>(fw1, fw1T);
    snn_main<<<512, 768, 0, stream>>>(x, w1, b1, w2, b2, w3, b3,
                                      fw1T, fb1, fw2, fb2, out);
}

// Round 3
// 679.540 us; speedup vs baseline: 2.5685x; 2.5685x over previous
//
#include <hip/hip_runtime.h>
#include <stdint.h>

#define BETA 0.9f

// ---------------------------------------------------------------------------
// Kernel 1: transpose fw1 (256, 1152) -> fw1T (1152, 256) so the fc1 spike
// row-gather is coalesced (row i = 256 contiguous floats = 1KB).
// ---------------------------------------------------------------------------
__global__ void transpose_fw1(const float* __restrict__ A, float* __restrict__ At) {
    __shared__ float tile[32][33];
    const int i0 = blockIdx.x * 32;   // i dim (1152)
    const int j0 = blockIdx.y * 32;   // j dim (256)
    const int tx = threadIdx.x, ty = threadIdx.y;
    for (int r = ty; r < 32; r += 8)
        tile[r][tx] = A[(j0 + r) * 1152 + i0 + tx];      // coalesced read over i
    __syncthreads();
    for (int r = ty; r < 32; r += 8)
        At[(i0 + r) * 256 + j0 + tx] = tile[tx][r];      // coalesced write over j
}

// ---------------------------------------------------------------------------
// Kernel 2: R19 = R16 tasks verbatim, rescheduled into TWO barrier phases/t:
//   P1: conv2(t) [waves 0-4] + reduce+LIF4(t-2) [wave 5, R16-idle in conv2]
//       + rm1/cm2 parity zeroing + x(t+1) prefetch
//   P2: conv1(t+1) + conv3(t) + fc1-partials(t-1) + fc2(t-2)
// masks gains a t&1 parity (written by conv3(t), read by fc1(t-1) same phase).
// All per-output FP chains / thread maps / batch orders are IDENTICAL to R16
// (absmax 0.0 expected). Live-state additions: m4q[4]+fb1q[4] on wave 5 only
// (R18 lesson: keep the ~40-VGPR envelope; do NOT merge heavy role state).
// Race audit (producer -> consumer, barrier between):
//   s1e:   P2(t) conv1 -> P1(t+1) conv2            (phase-end barrier)
//   rm1:   P2(t) conv1[pn] -> P1(t+1) conv2[pb]; zero pn in P1(t) (last read
//          of that parity was P1(t-1); next Or in P2(t) after b2)
//   cm2:   P1(t) conv2[pb] -> P2(t) conv3[pb]; zero pn in P1(t) (last read
//          P2(t-1); next Or P1(t+1))
//   masks: P2(t) conv3[pb] -> P2(t+1) fc1[sp=pb]   (phase-end barrier, x2 buf)
//   pacc:  P2(t) fc1 -> P1(t+1) reduce             (phase-end barrier)
//   s4:    P1(t) reduce -> P2(t) fc2               (b2)
// ---------------------------------------------------------------------------
__global__ __launch_bounds__(768)
__attribute__((amdgpu_waves_per_eu(6)))
void snn_main(
    const float* __restrict__ x,      // (1024, 1, 30, 100)
    const float* __restrict__ w1, const float* __restrict__ b1,
    const float* __restrict__ w2, const float* __restrict__ b2,
    const float* __restrict__ w3, const float* __restrict__ b3,
    const float* __restrict__ fw1T,   // (1152, 256) transposed
    const float* __restrict__ fb1,
    const float* __restrict__ fw2, const float* __restrict__ fb2,
    float* __restrict__ out)          // (100, 1024, 10)
{
    const int b    = blockIdx.x;
    const int tid  = threadIdx.x;
    const int e    = (tid >= 384) ? 1 : 0;   // element slot (waves 0-5 / 6-11)
    const int tl   = tid - 384 * e;          // per-element thread id (0..383)
    const int lane = tid & 63;               // hw-wave lane
    const int ew   = tl >> 6;                // per-element wave 0..5

    __shared__ float w2L[16 * 5 * 32];  // [(ci*5+k)*32 + c2]  10 KB (shared)
    __shared__ float w3L[32 * 3 * 64];  // [(ci*3+k)*64 + c3]  24 KB (shared)
    __shared__ float pacc[2][6][256];   // fc1 per-wave partials  12 KB
    __shared__ float s1e[2][16 * 24 + 8];
    __shared__ float s4[2][256];
    __shared__ unsigned long long masks[2][2][18];  // [e][t&1][l] s3 spikes
    __shared__ unsigned int rm1[2][2][16];  // s1 row masks (bit l), t-parity
    __shared__ unsigned int cm2[2][2][20];  // s2 per-l channel masks, t-parity

    // ---- static per-thread roles (within element, 6 waves) ----
    const int c1 = tl & 15;             // conv1: channel (all 384 active)
    const int l1 = tl >> 4;             // conv1: l (0..23), exactly one each
    const int c2 = tl & 31;             // conv2: channel
    const int g2 = tl >> 5;             // conv2: l-group 0..11 (10-11 = wave 5)
    const int l02 = 2 * g2;             // pair start
    const bool c2on = (ew < 5);         // conv2 active = waves 0-4 exactly
    const unsigned wmask2 = 0x3Fu << l02;
    const int c3 = lane;                // conv3: out channel
    const int l03 = ew * 3;             // conv3: 3 positions per wave (uniform)
    const int rl = tl - 320;            // reduce role (wave 5): j = rl + 64*q

    // ---- stage weights into LDS (shared by both elements) ----
    for (int i = tid; i < 16 * 5 * 32; i += 768) {
        const int cc = i & 31, r = i >> 5;          // r = ci*5+k
        w2L[i] = w2[cc * 80 + r];
    }
    for (int i = tid; i < 32 * 3 * 64; i += 768) {
        const int cc = i & 63, r = i >> 6;          // r = ci*3+k
        w3L[i] = w3[cc * 96 + r];
    }
    if (tl < 16) { rm1[e][0][tl] = 0u; rm1[e][1][tl] = 0u; }
    if (tl < 20) { cm2[e][0][tl] = 0u; cm2[e][1][tl] = 0u; }
    if (tl < 8)  s1e[e][384 + tl] = 0.0f;

    // ---- per-thread register state ----
    float w1r[7];
#pragma unroll
    for (int k = 0; k < 7; ++k) w1r[k] = w1[c1 * 7 + k];
    const float b1r = b1[c1];
    const float b2r = b2[c2];
    const float b3r = b3[c3];
    const int jf = tl >> 4, chf = tl & 15;           // fc2 roles (tl<160)
    const float fb2r = (tl < 160 && chf == 0) ? fb2[jf] : 0.0f;
    float fb1q[4];                                   // reduce bias (wave 5)
#pragma unroll
    for (int q = 0; q < 4; ++q)
        fb1q[q] = (ew == 5) ? fb1[rl + 64 * q] : 0.0f;

    float m1 = 0.f;
    float m2[2] = {0.f, 0.f};
    float m3[3] = {0.f, 0.f, 0.f};
    float m4q[4] = {0.f, 0.f, 0.f, 0.f};
    float m5 = 0.f;

    const float* xb = x + (2 * b + e) * 3000;
    const int out_b = (2 * b + e) * 10;
    const float4* fw1Tv = reinterpret_cast<const float4*>(fw1T);

    // x register load for t=0 (overlaps the staging barrier)
    float xr[7];
#pragma unroll
    for (int k = 0; k < 7; ++k) xr[k] = xb[(l1 + k) * 100];

    __syncthreads();   // staging -> compute

    // ---- peeled conv1(t=0) ----
    {
        float h = b1r;
#pragma unroll
        for (int k = 0; k < 7; ++k) h += xr[k] * w1r[k];
        float rs = (m1 > 1.0f) ? 1.0f : 0.0f;
        m1 = BETA * m1 + h - rs;
        float sa = (m1 > 1.0f) ? 1.0f : 0.0f;
        s1e[e][c1 * 24 + l1] = sa;
        if (sa != 0.0f) atomicOr(&rm1[e][0][c1], 1u << l1);
    }
    __syncthreads();   // conv1(0) -> pipeline

    for (int tau = 0; tau < 102; ++tau) {
        const int pb = tau & 1, pn = pb ^ 1;

        // ================= P1: conv2(tau) + reduce(tau-2) =================
        if (tl < 16) rm1[e][pn][tl] = 0u;   // parity for step tau+1
        if (tl < 20) cm2[e][pn][tl] = 0u;
        // issue x(tau+1) loads early: consumed by conv1(tau+1) in P2
        if (tau <= 98) {
#pragma unroll
            for (int k = 0; k < 7; ++k) xr[k] = xb[(l1 + k) * 100 + tau + 1];
        }
        if (c2on) {
            if (tau <= 99) {
                // ---- conv2 + LIF2 (R16 body verbatim) ----
                float h[2] = {b2r, b2r};
#pragma unroll
                for (int ci = 0; ci < 16; ++ci) {
                    const unsigned rmv =
                        __builtin_amdgcn_readfirstlane(rm1[e][pb][ci]);
                    if ((rmv & wmask2) == 0u) continue;   // exact: 0*w skipped
                    float win[6];
#pragma unroll
                    for (int r = 0; r < 6; ++r) win[r] = s1e[e][ci * 24 + l02 + r];
                    float wk[5];
#pragma unroll
                    for (int k = 0; k < 5; ++k) wk[k] = w2L[(ci * 5 + k) * 32 + c2];
#pragma unroll
                    for (int li = 0; li < 2; ++li)
#pragma unroll
                        for (int k = 0; k < 5; ++k) h[li] += win[li + k] * wk[k];
                }
#pragma unroll
                for (int li = 0; li < 2; ++li) {
                    float rs = (m2[li] > 1.0f) ? 1.0f : 0.0f;
                    m2[li] = BETA * m2[li] + h[li] - rs;
                    if (m2[li] > 1.0f) atomicOr(&cm2[e][pb][l02 + li], 1u << c2);
                }
            }
        } else {
            // ---- wave 5: fc1 reduce + LIF4 (step tau-2), R16 chain per j ----
            if (tau >= 2) {
#pragma unroll
                for (int q = 0; q < 4; ++q) {
                    const int j = rl + 64 * q;
                    float acc = fb1q[q];
#pragma unroll
                    for (int w = 0; w < 6; ++w) acc += pacc[e][w][j];
                    float rs = (m4q[q] > 1.0f) ? 1.0f : 0.0f;
                    m4q[q] = BETA * m4q[q] + acc - rs;
                    s4[e][j] = (m4q[q] > 1.0f) ? 1.0f : 0.0f;
                }
            }
        }
        __syncthreads();   // b2

        // ====== P2: conv1(tau+1) + conv3(tau) + fc1(tau-1) + fc2(tau-2) ======
        // ---- conv1(tau+1): R16 body verbatim ----
        if (tau <= 98) {
            float h = b1r;
#pragma unroll
            for (int k = 0; k < 7; ++k) h += xr[k] * w1r[k];
            float rs = (m1 > 1.0f) ? 1.0f : 0.0f;
            m1 = BETA * m1 + h - rs;
            float sa = (m1 > 1.0f) ? 1.0f : 0.0f;
            s1e[e][c1 * 24 + l1] = sa;
            if (sa != 0.0f) atomicOr(&rm1[e][pn][c1], 1u << l1);
        }

        // ---- conv3 + LIF3 (tau): R16 body, masks gains t&1 parity ----
        if (tau <= 99) {
            float h[3] = {b3r, b3r, b3r};
#pragma unroll
            for (int wl = 0; wl < 5; ++wl) {   // window positions l03..l03+4
                unsigned cm = __builtin_amdgcn_readfirstlane(cm2[e][pb][l03 + wl]);
                while (cm) {               // scalar mask walk
                    const int ci = (int)__builtin_ctz(cm); cm &= cm - 1;
                    const float* wp = &w3L[ci * 192 + c3];   // + k*64
#pragma unroll
                    for (int k = 0; k < 3; ++k) {
                        const int li = wl - k;               // compile-time
                        if (li >= 0 && li < 3)
                            h[li] += wp[k * 64];             // ds_read imm offset
                    }
                }
            }
#pragma unroll
            for (int li = 0; li < 3; ++li) {
                float rs = (m3[li] > 1.0f) ? 1.0f : 0.0f;
                m3[li] = BETA * m3[li] + h[li] - rs;
                float s = (m3[li] > 1.0f) ? 1.0f : 0.0f;
                unsigned long long mk = __ballot(s != 0.0f);
                if (lane == 0) masks[e][pb][l03 + li] = mk;
            }
        }

        // ---- fc1 partials (step tau-1): R16 body verbatim, masks[pn] ----
        if (tau >= 1 && tau <= 100) {
            float4 acc4; acc4.x = acc4.y = acc4.z = acc4.w = 0.0f;
#pragma unroll 1
            for (int l = ew; l < 18; l += 6) {     // wave-uniform trip count
                const unsigned* mp = (const unsigned*)&masks[e][pn][l];
                const unsigned mlo = __builtin_amdgcn_readfirstlane(mp[0]);
                const unsigned mhi = __builtin_amdgcn_readfirstlane(mp[1]);
                unsigned long long mk = ((unsigned long long)mhi << 32) | mlo;
                while (mk) {   // 4-wide float4 batching, whole row per wave
                    float4 f0, f1, f2, f3;
                    f0.x=f0.y=f0.z=f0.w=0.f; f1=f0; f2=f0; f3=f0;
                    int c;
                    c = (int)__builtin_ctzll(mk); mk &= mk - 1;
                    f0 = fw1Tv[(c * 18 + l) * 64 + lane];
                    if (mk) { c = (int)__builtin_ctzll(mk); mk &= mk - 1;
                              f1 = fw1Tv[(c * 18 + l) * 64 + lane]; }
                    if (mk) { c = (int)__builtin_ctzll(mk); mk &= mk - 1;
                              f2 = fw1Tv[(c * 18 + l) * 64 + lane]; }
                    if (mk) { c = (int)__builtin_ctzll(mk); mk &= mk - 1;
                              f3 = fw1Tv[(c * 18 + l) * 64 + lane]; }
                    acc4.x += f0.x; acc4.y += f0.y; acc4.z += f0.z; acc4.w += f0.w;
                    acc4.x += f1.x; acc4.y += f1.y; acc4.z += f1.z; acc4.w += f1.w;
                    acc4.x += f2.x; acc4.y += f2.y; acc4.z += f2.z; acc4.w += f2.w;
                    acc4.x += f3.x; acc4.y += f3.y; acc4.z += f3.z; acc4.w += f3.w;
                }
            }
            ((float4*)&pacc[e][ew][0])[lane] = acc4;   // partial for j=lane*4+k
        }

        // ---- fc2 (step tau-2): R16 body verbatim, reads s4 written in P1 ----
        if (tau >= 2 && tl < 160) {
            const int t5 = tau - 2;
            const float* wrow = fw2 + jf * 256;   // L1-hot (10KB, reused)
            float p = 0.f;
#pragma unroll
            for (int i = 0; i < 16; ++i)
                p += s4[e][i * 16 + chf] * wrow[i * 16 + chf];
            p += __shfl_xor(p, 8, 16);
            p += __shfl_xor(p, 4, 16);
            p += __shfl_xor(p, 2, 16);
            p += __shfl_xor(p, 1, 16);
            if (chf == 0) {
                float h = fb2r + p;
                float rs = (m5 > 1.0f) ? 1.0f : 0.0f;
                m5 = BETA * m5 + h - rs;
                out[t5 * 10240 + out_b + jf] = (m5 > 1.0f) ? 1.0f : 0.0f;
            }
        }
        __syncthreads();   // phase-end
    }
}

extern "C" void kernel_launch(void* const* d_in, const int* in_sizes, int n_in,
                              void* d_out, int out_size, void* d_ws, size_t ws_size,
                              hipStream_t stream) {
    const float* x   = (const float*)d_in[0];
    const float* w1  = (const float*)d_in[1];
    const float* b1  = (const float*)d_in[2];
    const float* w2  = (const float*)d_in[3];
    const float* b2  = (const float*)d_in[4];
    const float* w3  = (const float*)d_in[5];
    const float* b3  = (const float*)d_in[6];
    const float* fw1 = (const float*)d_in[7];
    const float* fb1 = (const float*)d_in[8];
    const float* fw2 = (const float*)d_in[9];
    const float* fb2 = (const float*)d_in[10];
    float* out  = (float*)d_out;
    float* fw1T = (float*)d_ws;   // 1152*256*4 = 1.18 MB

    dim3 tb(32, 8);
    dim3 tg(1152 / 32, 256 / 32);
    transpose_fw1<<<tg, tb, 0, stream>>>(fw1, fw1T);
    snn_main<<<512, 768, 0, stream>>>(x, w1, b1, w2, b2, w3, b3,
                                      fw1T, fb1, fw2, fb2, out);
}

// Round 4
// 677.851 us; speedup vs baseline: 2.5749x; 1.0025x over previous
//
#include <hip/hip_runtime.h>
#include <stdint.h>

#define BETA 0.9f

// ---------------------------------------------------------------------------
// Kernel 1: transpose fw1 (256, 1152) -> fw1T (1152, 256) so the fc1 spike
// row-gather is coalesced (row i = 256 contiguous floats = 1KB).
// ---------------------------------------------------------------------------
__global__ void transpose_fw1(const float* __restrict__ A, float* __restrict__ At) {
    __shared__ float tile[32][33];
    const int i0 = blockIdx.x * 32;   // i dim (1152)
    const int j0 = blockIdx.y * 32;   // j dim (256)
    const int tx = threadIdx.x, ty = threadIdx.y;
    for (int r = ty; r < 32; r += 8)
        tile[r][tx] = A[(j0 + r) * 1152 + i0 + tx];      // coalesced read over i
    __syncthreads();
    for (int r = ty; r < 32; r += 8)
        At[(i0 + r) * 256 + j0 + tx] = tile[tx][r];      // coalesced write over j
}

// ---------------------------------------------------------------------------
// Kernel 2: R20 = R16 structure with LDS/issue-work cuts (R19 post-mortem:
// barriers were not the bottleneck; LDS reads + per-thread issue are).
//   1. BINARY conv2: win[6]/s1e eliminated. rm1 bits (wave-uniform) select
//      wk[k] adds via compile-time-indexed scalar-branched adds.
//      fma(0,w,h)==h and fma(1,w,h)==h+w exactly; same k order -> bit-exact.
//      Removes 6 of 11 LDS reads per ci per thread + all multiplies.
//   2. conv3 weights re-laid [ci][c3][k] (k contiguous) -> fused b64/b96
//      reads (1 instr/spike instead of 3), same bytes, same add order.
//   3. reduce+LIF4(tau-1) folded onto wave 5 during conv2 phase (idle there);
//      fc2(tau-1) folded into conv3 phase. 3 barriers/t instead of 4.
// Race audit (all pairs cross >=1 barrier):
//   rm1:  conv1(t+1)@P3 Or[pn] -> conv2(t+1)@P1 rd[pb'] (phase-end);
//         zero[pn]@P1(t) vs Or[pn]@P3(t) (b2,b3); last rd of pn @P1(t-1).
//   cm2:  conv2(t)@P1 Or[pb] -> conv3(t)@P2 rd[pb] (b2); zero[pn]@P1(t):
//         last rd @P2(t-1), next Or @P1(t+1).
//   masks: conv3(t)@P2 -> fc1(t)@P3 (b3); next wr @P2(t+1) (phase-end,b2).
//   pacc: fc1(t)@P3 -> reduce(t)@P1(t+1) (phase-end); next wr @P3(t+1).
//   s4:   reduce(t-1)@P1 -> fc2(t-1)@P2 (b2); next wr @P1(t+1) (b3,phase-end).
// ---------------------------------------------------------------------------
__global__ __launch_bounds__(768)
__attribute__((amdgpu_waves_per_eu(6)))
void snn_main(
    const float* __restrict__ x,      // (1024, 1, 30, 100)
    const float* __restrict__ w1, const float* __restrict__ b1,
    const float* __restrict__ w2, const float* __restrict__ b2,
    const float* __restrict__ w3, const float* __restrict__ b3,
    const float* __restrict__ fw1T,   // (1152, 256) transposed
    const float* __restrict__ fb1,
    const float* __restrict__ fw2, const float* __restrict__ fb2,
    float* __restrict__ out)          // (100, 1024, 10)
{
    const int b    = blockIdx.x;
    const int tid  = threadIdx.x;
    const int e    = (tid >= 384) ? 1 : 0;   // element slot (waves 0-5 / 6-11)
    const int tl   = tid - 384 * e;          // per-element thread id (0..383)
    const int lane = tid & 63;               // hw-wave lane
    const int ew   = tl >> 6;                // per-element wave 0..5

    __shared__ float w2L[16 * 5 * 32];   // [(ci*5+k)*32 + c2]   10 KB (shared)
    __shared__ float w3L[32 * 64 * 3];   // [ci*192 + c3*3 + k]  24 KB (shared)
    __shared__ float pacc[2][6][256];    // fc1 per-wave partials 12 KB
    __shared__ float s4[2][256];         // 2 KB
    __shared__ unsigned long long masks[2][18];  // s3 spikes (bit = channel)
    __shared__ unsigned int rm1[2][2][16];  // s1 row masks (bit l), t-parity
    __shared__ unsigned int cm2[2][2][20];  // s2 per-l channel masks, t-parity

    // ---- static per-thread roles (within element, 6 waves) ----
    const int c1 = tl & 15;             // conv1: channel (all 384 active)
    const int l1 = tl >> 4;             // conv1: l (0..23), exactly one each
    const int c2 = tl & 31;             // conv2: channel
    const int g2 = tl >> 5;             // conv2: l-group 0..11 (10-11 = wave 5)
    const int l02 = 2 * g2;             // pair start
    const bool c2w = (ew < 5);          // conv2 active = waves 0-4 exactly
    const int c3 = lane;                // conv3: out channel
    const int l03 = ew * 3;             // conv3: 3 positions per wave (uniform)
    const int rl = tl - 320;            // reduce role (wave 5): j = rl + 64*q

    // ---- stage weights into LDS (shared by both elements) ----
    for (int i = tid; i < 16 * 5 * 32; i += 768) {
        const int cc = i & 31, r = i >> 5;          // r = ci*5+k
        w2L[i] = w2[cc * 80 + r];
    }
    for (int i = tid; i < 32 * 64 * 3; i += 768) {
        const int ci = i / 192, r2 = i - ci * 192;
        const int cc = r2 / 3, k = r2 - cc * 3;
        w3L[i] = w3[cc * 96 + ci * 3 + k];
    }
    if (tl < 16) { rm1[e][0][tl] = 0u; rm1[e][1][tl] = 0u; }
    if (tl < 20) { cm2[e][0][tl] = 0u; cm2[e][1][tl] = 0u; }

    // ---- per-thread register state ----
    float w1r[7];
#pragma unroll
    for (int k = 0; k < 7; ++k) w1r[k] = w1[c1 * 7 + k];
    const float b1r = b1[c1];
    const float b2r = b2[c2];
    const float b3r = b3[c3];
    const int jf = tl >> 4, chf = tl & 15;           // fc2 roles (tl<160)
    const float fb2r = (tl < 160 && chf == 0) ? fb2[jf] : 0.0f;
    float fb1q[4];                                   // reduce bias (wave 5)
#pragma unroll
    for (int q = 0; q < 4; ++q)
        fb1q[q] = (ew == 5) ? fb1[rl + 64 * q] : 0.0f;

    float m1 = 0.f;
    float m2[2] = {0.f, 0.f};
    float m3[3] = {0.f, 0.f, 0.f};
    float m4q[4] = {0.f, 0.f, 0.f, 0.f};
    float m5 = 0.f;

    const float* xb = x + (2 * b + e) * 3000;
    const int out_b = (2 * b + e) * 10;
    const float4* fw1Tv = reinterpret_cast<const float4*>(fw1T);

    // x register load for t=0 (overlaps the staging barrier)
    float xr[7];
#pragma unroll
    for (int k = 0; k < 7; ++k) xr[k] = xb[(l1 + k) * 100];

    __syncthreads();   // staging -> compute

    // ---- peeled conv1(t=0): rm1 bits only (s1e eliminated) ----
    {
        float h = b1r;
#pragma unroll
        for (int k = 0; k < 7; ++k) h += xr[k] * w1r[k];
        float rs = (m1 > 1.0f) ? 1.0f : 0.0f;
        m1 = BETA * m1 + h - rs;
        if (m1 > 1.0f) atomicOr(&rm1[e][0][c1], 1u << l1);
    }
    __syncthreads();   // conv1(0) -> pipeline

    for (int tau = 0; tau <= 100; ++tau) {
        const int pb = tau & 1, pn = pb ^ 1;

        // ========== P1: conv2(tau) [waves 0-4] + reduce(tau-1) [wave 5] =====
        if (tl < 16) rm1[e][pn][tl] = 0u;   // parity for step tau+1
        if (tl < 20) cm2[e][pn][tl] = 0u;
        // issue x(tau+1) loads early: consumed by conv1(tau+1) in P3
        if (tau <= 98) {
#pragma unroll
            for (int k = 0; k < 7; ++k) xr[k] = xb[(l1 + k) * 100 + tau + 1];
        }
        if (c2w) {
            if (tau <= 99) {
                // ---- BINARY conv2: rm1 bits select wk adds (bit-exact) ----
                float h0 = b2r, h1 = b2r;
#pragma unroll
                for (int ci = 0; ci < 16; ++ci) {
                    const unsigned rmv =
                        __builtin_amdgcn_readfirstlane(rm1[e][pb][ci]);
                    const unsigned wb = (rmv >> l02) & 0x3Fu;
                    if (wb == 0u) continue;     // exact: skipped terms 0*w
                    float wk[5];
#pragma unroll
                    for (int k = 0; k < 5; ++k)
                        wk[k] = w2L[(ci * 5 + k) * 32 + c2];
                    // h0: window bits 0..4 -> wk[0..4] (k ascending, as R16)
                    // h1: window bits 1..5 -> wk[0..4] (k ascending, as R16)
                    if (wb & 1u)  h0 += wk[0];
                    if (wb & 2u)  { h0 += wk[1]; h1 += wk[0]; }
                    if (wb & 4u)  { h0 += wk[2]; h1 += wk[1]; }
                    if (wb & 8u)  { h0 += wk[3]; h1 += wk[2]; }
                    if (wb & 16u) { h0 += wk[4]; h1 += wk[3]; }
                    if (wb & 32u) h1 += wk[4];
                }
                {
                    float rs = (m2[0] > 1.0f) ? 1.0f : 0.0f;
                    m2[0] = BETA * m2[0] + h0 - rs;
                    if (m2[0] > 1.0f) atomicOr(&cm2[e][pb][l02], 1u << c2);
                    rs = (m2[1] > 1.0f) ? 1.0f : 0.0f;
                    m2[1] = BETA * m2[1] + h1 - rs;
                    if (m2[1] > 1.0f) atomicOr(&cm2[e][pb][l02 + 1], 1u << c2);
                }
            }
        } else if (tau >= 1) {
            // ---- wave 5: fc1 reduce + LIF4 (step tau-1), R16 chain per j ----
#pragma unroll
            for (int q = 0; q < 4; ++q) {
                const int j = rl + 64 * q;
                float acc = fb1q[q];
#pragma unroll
                for (int w = 0; w < 6; ++w) acc += pacc[e][w][j];
                float rs = (m4q[q] > 1.0f) ? 1.0f : 0.0f;
                m4q[q] = BETA * m4q[q] + acc - rs;
                s4[e][j] = (m4q[q] > 1.0f) ? 1.0f : 0.0f;
            }
        }
        __syncthreads();   // b2

        // ========== P2: conv3(tau) + fc2(tau-1) ==========
        if (tau <= 99) {
            float h[3] = {b3r, b3r, b3r};
#pragma unroll
            for (int wl = 0; wl < 5; ++wl) {   // window positions l03..l03+4
                unsigned cm = __builtin_amdgcn_readfirstlane(cm2[e][pb][l03 + wl]);
                while (cm) {               // scalar mask walk
                    const int ci = (int)__builtin_ctz(cm); cm &= cm - 1;
                    const float* wp = &w3L[ci * 192 + c3 * 3];  // k contiguous
#pragma unroll
                    for (int k = 0; k < 3; ++k) {
                        const int li = wl - k;               // compile-time
                        if (li >= 0 && li < 3)
                            h[li] += wp[k];          // fused ds_read b64/b96
                    }
                }
            }
#pragma unroll
            for (int li = 0; li < 3; ++li) {
                float rs = (m3[li] > 1.0f) ? 1.0f : 0.0f;
                m3[li] = BETA * m3[li] + h[li] - rs;
                float s = (m3[li] > 1.0f) ? 1.0f : 0.0f;
                unsigned long long mk = __ballot(s != 0.0f);
                if (lane == 0) masks[e][l03 + li] = mk;
            }
        }
        // ---- fc2 (step tau-1): R16 body, reads s4 written in P1 ----
        if (tau >= 1 && tl < 160) {
            const int t5 = tau - 1;
            const float* wrow = fw2 + jf * 256;   // L1-hot (10KB, reused)
            float p = 0.f;
#pragma unroll
            for (int i = 0; i < 16; ++i)
                p += s4[e][i * 16 + chf] * wrow[i * 16 + chf];
            p += __shfl_xor(p, 8, 16);
            p += __shfl_xor(p, 4, 16);
            p += __shfl_xor(p, 2, 16);
            p += __shfl_xor(p, 1, 16);
            if (chf == 0) {
                float h = fb2r + p;
                float rs = (m5 > 1.0f) ? 1.0f : 0.0f;
                m5 = BETA * m5 + h - rs;
                out[t5 * 10240 + out_b + jf] = (m5 > 1.0f) ? 1.0f : 0.0f;
            }
        }
        __syncthreads();   // b3

        // ========== P3: conv1(tau+1) + fc1(tau) ==========
        if (tau <= 98) {
            float h = b1r;
#pragma unroll
            for (int k = 0; k < 7; ++k) h += xr[k] * w1r[k];
            float rs = (m1 > 1.0f) ? 1.0f : 0.0f;
            m1 = BETA * m1 + h - rs;
            if (m1 > 1.0f) atomicOr(&rm1[e][pn][c1], 1u << l1);
        }

        // ---- fc1 partials (step tau): R16 body verbatim (FROZEN form) ----
        if (tau <= 99) {
            float4 acc4; acc4.x = acc4.y = acc4.z = acc4.w = 0.0f;
#pragma unroll 1
            for (int l = ew; l < 18; l += 6) {     // wave-uniform trip count
                const unsigned* mp = (const unsigned*)&masks[e][l];
                const unsigned mlo = __builtin_amdgcn_readfirstlane(mp[0]);
                const unsigned mhi = __builtin_amdgcn_readfirstlane(mp[1]);
                unsigned long long mk = ((unsigned long long)mhi << 32) | mlo;
                while (mk) {   // 4-wide float4 batching, whole row per wave
                    float4 f0, f1, f2, f3;
                    f0.x=f0.y=f0.z=f0.w=0.f; f1=f0; f2=f0; f3=f0;
                    int c;
                    c = (int)__builtin_ctzll(mk); mk &= mk - 1;
                    f0 = fw1Tv[(c * 18 + l) * 64 + lane];
                    if (mk) { c = (int)__builtin_ctzll(mk); mk &= mk - 1;
                              f1 = fw1Tv[(c * 18 + l) * 64 + lane]; }
                    if (mk) { c = (int)__builtin_ctzll(mk); mk &= mk - 1;
                              f2 = fw1Tv[(c * 18 + l) * 64 + lane]; }
                    if (mk) { c = (int)__builtin_ctzll(mk); mk &= mk - 1;
                              f3 = fw1Tv[(c * 18 + l) * 64 + lane]; }
                    acc4.x += f0.x; acc4.y += f0.y; acc4.z += f0.z; acc4.w += f0.w;
                    acc4.x += f1.x; acc4.y += f1.y; acc4.z += f1.z; acc4.w += f1.w;
                    acc4.x += f2.x; acc4.y += f2.y; acc4.z += f2.z; acc4.w += f2.w;
                    acc4.x += f3.x; acc4.y += f3.y; acc4.z += f3.z; acc4.w += f3.w;
                }
            }
            ((float4*)&pacc[e][ew][0])[lane] = acc4;   // partial for j=lane*4+k
        }
        __syncthreads();   // phase-end
    }
}

extern "C" void kernel_launch(void* const* d_in, const int* in_sizes, int n_in,
                              void* d_out, int out_size, void* d_ws, size_t ws_size,
                              hipStream_t stream) {
    const float* x   = (const float*)d_in[0];
    const float* w1  = (const float*)d_in[1];
    const float* b1  = (const float*)d_in[2];
    const float* w2  = (const float*)d_in[3];
    const float* b2  = (const float*)d_in[4];
    const float* w3  = (const float*)d_in[5];
    const float* b3  = (const float*)d_in[6];
    const float* fw1 = (const float*)d_in[7];
    const float* fb1 = (const float*)d_in[8];
    const float* fw2 = (const float*)d_in[9];
    const float* fb2 = (const float*)d_in[10];
    float* out  = (float*)d_out;
    float* fw1T = (float*)d_ws;   // 1152*256*4 = 1.18 MB

    dim3 tb(32, 8);
    dim3 tg(1152 / 32, 256 / 32);
    transpose_fw1<<<tg, tb, 0, stream>>>(fw1, fw1T);
    snn_main<<<512, 768, 0, stream>>>(x, w1, b1, w2, b2, w3, b3,
                                      fw1T, fb1, fw2, fb2, out);
}